// Round 1
// baseline (165.573 us; speedup 1.0000x reference)
//
#include <hip/hip_runtime.h>

#define NROWS 4096
#define DIM   256
#define MARGINF 0.3f

#define BM 128
#define BN 128
#define BK 16
#define PITCH 192   // 128 data floats + 4-float pad per 8-float group (16 groups)
#define CS 16       // column slices

// ---- order-preserving float<->uint encoding for atomic max/min ----
__device__ __forceinline__ unsigned enc_f(float f) {
  unsigned u = __float_as_uint(f);
  return (u & 0x80000000u) ? ~u : (u | 0x80000000u);
}
__device__ __forceinline__ float dec_f(unsigned k) {
  unsigned u = (k & 0x80000000u) ? (k ^ 0x80000000u) : ~k;
  return __uint_as_float(u);
}

__global__ void k_init(unsigned* __restrict__ posk, unsigned* __restrict__ negk) {
  int i = blockIdx.x * 256 + threadIdx.x;
  if (i < NROWS) { posk[i] = enc_f(-1e30f); negk[i] = enc_f(1e30f); }
}

// one wave per row: sq_norm[i] = sum_k F[i][k]^2
__global__ void k_sqnorm(const float* __restrict__ F, float* __restrict__ nrm) {
  int row = blockIdx.x;
  int l = threadIdx.x;                       // 0..63
  const float4 v = *(const float4*)&F[row * DIM + l * 4];
  float s = v.x * v.x + v.y * v.y + v.z * v.z + v.w * v.w;
  #pragma unroll
  for (int off = 32; off; off >>= 1) s += __shfl_down(s, off);
  if (l == 0) nrm[row] = s;
}

// Fused Gram-tile + batch-hard mining.
// grid = 32 row-tiles * CS col-slices; block = 256 threads; 8x8 micro-tile.
__global__ __launch_bounds__(256, 2) void k_tiles(
    const float* __restrict__ F, const int* __restrict__ lab,
    const float* __restrict__ nrm,
    unsigned* __restrict__ posk, unsigned* __restrict__ negk) {
  __shared__ float As[BK * PITCH];
  __shared__ float Bs[BK * PITCH];

  const int tid = threadIdx.x;
  const int tm = tid & 15, tn = tid >> 4;
  const int bx = blockIdx.x;
  const int rt = bx & 31;        // 32 row tiles
  const int cs = bx >> 5;        // CS col slices of 256 columns
  const int row0 = rt * BM;

  int li[8]; float ni[8];
  #pragma unroll
  for (int r = 0; r < 8; ++r) {
    int i = row0 + tm * 8 + r;
    li[r] = lab[i];
    ni[r] = nrm[i];
  }

  float posv[8], negv[8];
  #pragma unroll
  for (int r = 0; r < 8; ++r) { posv[r] = -1e30f; negv[r] = 1e30f; }

  for (int jt = 0; jt < 2; ++jt) {
    const int jbase = cs * 256 + jt * BN;

    float acc[8][8];
    #pragma unroll
    for (int r = 0; r < 8; ++r)
      #pragma unroll
      for (int c = 0; c < 8; ++c) acc[r][c] = 0.f;

    for (int kt = 0; kt < DIM / BK; ++kt) {
      // stage A & B tiles transposed: element (k, m) -> buf[k*PITCH + m + (m/8)*4]
      #pragma unroll
      for (int s = 0; s < 2; ++s) {
        int f = tid + s * 256;           // 0..511 float4 slots
        int r = f >> 2;                  // 0..127 row-in-tile
        int kq = (f & 3) << 2;           // 0,4,8,12
        float4 va = *(const float4*)&F[(row0 + r) * DIM + kt * BK + kq];
        float4 vb = *(const float4*)&F[(jbase + r) * DIM + kt * BK + kq];
        int roff = r + ((r >> 3) << 2);
        As[(kq + 0) * PITCH + roff] = va.x;
        As[(kq + 1) * PITCH + roff] = va.y;
        As[(kq + 2) * PITCH + roff] = va.z;
        As[(kq + 3) * PITCH + roff] = va.w;
        Bs[(kq + 0) * PITCH + roff] = vb.x;
        Bs[(kq + 1) * PITCH + roff] = vb.y;
        Bs[(kq + 2) * PITCH + roff] = vb.z;
        Bs[(kq + 3) * PITCH + roff] = vb.w;
      }
      __syncthreads();
      #pragma unroll
      for (int k = 0; k < BK; ++k) {
        float4 a0 = *(const float4*)&As[k * PITCH + tm * 12];
        float4 a1 = *(const float4*)&As[k * PITCH + tm * 12 + 4];
        float4 b0 = *(const float4*)&Bs[k * PITCH + tn * 12];
        float4 b1 = *(const float4*)&Bs[k * PITCH + tn * 12 + 4];
        float a[8] = {a0.x, a0.y, a0.z, a0.w, a1.x, a1.y, a1.z, a1.w};
        float b[8] = {b0.x, b0.y, b0.z, b0.w, b1.x, b1.y, b1.z, b1.w};
        #pragma unroll
        for (int r = 0; r < 8; ++r)
          #pragma unroll
          for (int c = 0; c < 8; ++c)
            acc[r][c] = fmaf(a[r], b[c], acc[r][c]);
      }
      __syncthreads();
    }

    // mining epilogue for this j-tile (sq is monotone proxy for dist)
    #pragma unroll
    for (int c = 0; c < 8; ++c) {
      int j = jbase + tn * 8 + c;
      int ljc = lab[j];
      float nj = nrm[j];
      #pragma unroll
      for (int r = 0; r < 8; ++r) {
        int i = row0 + tm * 8 + r;
        float sq = ni[r] + nj - 2.f * acc[r][c];
        bool same = (li[r] == ljc);
        if (same) {
          if (i != j) posv[r] = fmaxf(posv[r], sq);
        } else {
          negv[r] = fminf(negv[r], sq);
        }
      }
    }
  }

  // block-level reduce across the 16 tn-groups, then one atomic per row
  float* red = As;  // 16*128 floats = 8KB, fits in As
  __syncthreads();
  #pragma unroll
  for (int r = 0; r < 8; ++r) red[tn * BM + tm * 8 + r] = posv[r];
  __syncthreads();
  if (tid < BM) {
    float m = -1e30f;
    #pragma unroll
    for (int g = 0; g < 16; ++g) m = fmaxf(m, red[g * BM + tid]);
    atomicMax(&posk[row0 + tid], enc_f(m));
  }
  __syncthreads();
  #pragma unroll
  for (int r = 0; r < 8; ++r) red[tn * BM + tm * 8 + r] = negv[r];
  __syncthreads();
  if (tid < BM) {
    float m = 1e30f;
    #pragma unroll
    for (int g = 0; g < 16; ++g) m = fminf(m, red[g * BM + tid]);
    atomicMin(&negk[row0 + tid], enc_f(m));
  }
}

__global__ void k_final(const unsigned* __restrict__ posk,
                        const unsigned* __restrict__ negk,
                        float* __restrict__ out) {
  int t = threadIdx.x;  // 1024 threads
  float sum = 0.f;
  int cnt = 0;
  for (int i = t; i < NROWS; i += 1024) {
    float ps = dec_f(posk[i]);
    float ns = dec_f(negk[i]);
    bool valid = (ps > -1e29f) && (ns < 1e29f);
    if (valid) {
      float hp = sqrtf(fmaxf(ps, 1e-12f));
      float hn = sqrtf(fmaxf(ns, 1e-12f));
      sum += fmaxf(hp - hn + MARGINF, 0.f);
      cnt += 1;
    }
  }
  #pragma unroll
  for (int off = 32; off; off >>= 1) {
    sum += __shfl_down(sum, off);
    cnt += __shfl_down(cnt, off);
  }
  __shared__ float wsum[16];
  __shared__ int wcnt[16];
  int w = t >> 6;
  if ((t & 63) == 0) { wsum[w] = sum; wcnt[w] = cnt; }
  __syncthreads();
  if (t == 0) {
    float S = 0.f; int C = 0;
    #pragma unroll
    for (int i = 0; i < 16; ++i) { S += wsum[i]; C += wcnt[i]; }
    out[0] = (C > 0) ? (S / (float)C) : 0.f;
  }
}

extern "C" void kernel_launch(void* const* d_in, const int* in_sizes, int n_in,
                              void* d_out, int out_size, void* d_ws, size_t ws_size,
                              hipStream_t stream) {
  const float* F = (const float*)d_in[0];
  const int* lab = (const int*)d_in[1];
  float* out = (float*)d_out;

  unsigned* posk = (unsigned*)d_ws;          // [NROWS]
  unsigned* negk = posk + NROWS;             // [NROWS]
  float* nrm = (float*)(negk + NROWS);       // [NROWS]

  k_init<<<(NROWS + 255) / 256, 256, 0, stream>>>(posk, negk);
  k_sqnorm<<<NROWS, 64, 0, stream>>>(F, nrm);
  k_tiles<<<32 * CS, 256, 0, stream>>>(F, lab, nrm, posk, negk);
  k_final<<<1, 1024, 0, stream>>>(posk, negk, out);
}

// Round 2
// 80.732 us; speedup vs baseline: 2.0509x; 2.0509x over previous
//
#include <hip/hip_runtime.h>

typedef unsigned short ushort_t;
typedef __attribute__((ext_vector_type(8))) short bf16x8;
typedef __attribute__((ext_vector_type(4))) float f32x4;

#define NROWS 4096
#define DIM   256
#define MARGINF 0.3f

// ---- order-preserving float<->uint encoding for atomic max/min ----
__device__ __forceinline__ unsigned enc_f(float f) {
  unsigned u = __float_as_uint(f);
  return (u & 0x80000000u) ? ~u : (u | 0x80000000u);
}
__device__ __forceinline__ float dec_f(unsigned k) {
  unsigned u = (k & 0x80000000u) ? (k ^ 0x80000000u) : ~k;
  return __uint_as_float(u);
}

__device__ __forceinline__ ushort_t f2b(float f) {  // fp32 -> bf16 bits, RNE
  unsigned u = __float_as_uint(f);
  u += 0x7fffu + ((u >> 16) & 1u);
  return (ushort_t)(u >> 16);
}

__device__ __forceinline__ void gload_lds16(const void* g, void* l) {
  __builtin_amdgcn_global_load_lds(
      (const __attribute__((address_space(1))) void*)g,
      (__attribute__((address_space(3))) void*)l, 16, 0, 0);
}

// Fused: fp32->bf16 convert, sq-norms, posk/negk init. 1024 blocks x 256.
__global__ void k_prep(const float* __restrict__ F, ushort_t* __restrict__ Fb,
                       float* __restrict__ nrm, unsigned* __restrict__ posk,
                       unsigned* __restrict__ negk) {
  const int tid = threadIdx.x;
  const int wave = tid >> 6, lane = tid & 63;
  const int row = blockIdx.x * 4 + wave;

  const float4 v = *(const float4*)&F[row * DIM + lane * 4];
  float s = fmaf(v.x, v.x, fmaf(v.y, v.y, fmaf(v.z, v.z, v.w * v.w)));
  #pragma unroll
  for (int off = 32; off; off >>= 1) s += __shfl_down(s, off);
  if (lane == 0) nrm[row] = s;

  ushort4 o;
  o.x = f2b(v.x); o.y = f2b(v.y); o.z = f2b(v.z); o.w = f2b(v.w);
  *(ushort4*)&Fb[row * DIM + lane * 4] = o;

  const int gid = blockIdx.x * 256 + tid;
  if (gid < NROWS) { posk[gid] = enc_f(-1e30f); negk[gid] = enc_f(1e30f); }
}

// Gram tile (128x128, bf16 MFMA) + fused batch-hard mining.
// grid = 32*32 blocks, 256 threads (4 waves as 2x2, each wave 64x64 = 4x4 frags).
__global__ __launch_bounds__(256, 2) void k_gram(
    const ushort_t* __restrict__ Fb, const int* __restrict__ lab,
    const float* __restrict__ nrm,
    unsigned* __restrict__ posk, unsigned* __restrict__ negk) {
  __shared__ alignas(16) ushort_t As[128 * 32];   // [row][k] linear, 8KB
  __shared__ alignas(16) ushort_t Bs[128 * 32];
  __shared__ int labi[128], labj[128];
  __shared__ float nrmi[128], nrmj[128];
  __shared__ float redp[2][128], redn[2][128];

  const int tid = threadIdx.x;
  const int wave = tid >> 6, lane = tid & 63;
  const int wm = wave >> 1, wn = wave & 1;
  const int rt = blockIdx.x & 31, ct = blockIdx.x >> 5;
  const int row0 = rt * 128, col0 = ct * 128;

  if (tid < 128) { labi[tid] = lab[row0 + tid]; nrmi[tid] = nrm[row0 + tid]; }
  else { int t = tid - 128; labj[t] = lab[col0 + t]; nrmj[t] = nrm[col0 + t]; }

  f32x4 acc[4][4];
  #pragma unroll
  for (int m = 0; m < 4; ++m)
    #pragma unroll
    for (int n = 0; n < 4; ++n) acc[m][n] = (f32x4){0.f, 0.f, 0.f, 0.f};

  const int lrow = lane >> 2;        // row within a 16-row staging chunk
  const int lcol = (lane & 3) * 8;   // k offset (ushorts) within the chunk

  for (int kk = 0; kk < 8; ++kk) {
    // stage A/B tiles: per wave, 2 chunks of 16 rows x 32 k (1KB per issue)
    #pragma unroll
    for (int s = 0; s < 2; ++s) {
      const int rbase = s * 64 + wave * 16;
      gload_lds16(&Fb[(row0 + rbase + lrow) * DIM + kk * 32 + lcol], &As[rbase * 32]);
      gload_lds16(&Fb[(col0 + rbase + lrow) * DIM + kk * 32 + lcol], &Bs[rbase * 32]);
    }
    __syncthreads();

    bf16x8 a[4], b[4];
    #pragma unroll
    for (int m = 0; m < 4; ++m)
      a[m] = *(const bf16x8*)&As[(wm * 64 + m * 16 + (lane & 15)) * 32 + (lane >> 4) * 8];
    #pragma unroll
    for (int n = 0; n < 4; ++n)
      b[n] = *(const bf16x8*)&Bs[(wn * 64 + n * 16 + (lane & 15)) * 32 + (lane >> 4) * 8];
    #pragma unroll
    for (int m = 0; m < 4; ++m)
      #pragma unroll
      for (int n = 0; n < 4; ++n)
        acc[m][n] = __builtin_amdgcn_mfma_f32_16x16x32_bf16(a[m], b[n], acc[m][n], 0, 0, 0);
    __syncthreads();
  }

  // ---- fused mining epilogue ----
  // C/D layout: col = lane&15, row = (lane>>4)*4 + reg_idx  [m89/m91]
  const int h = lane >> 4, ccol = lane & 15;
  float posr[4][4], negr[4][4];
  #pragma unroll
  for (int m = 0; m < 4; ++m)
    #pragma unroll
    for (int j = 0; j < 4; ++j) { posr[m][j] = -1e30f; negr[m][j] = 1e30f; }

  #pragma unroll
  for (int m = 0; m < 4; ++m) {
    #pragma unroll
    for (int n = 0; n < 4; ++n) {
      const int cl = wn * 64 + n * 16 + ccol;
      const float nj = nrmj[cl];
      const int lj = labj[cl];
      #pragma unroll
      for (int j = 0; j < 4; ++j) {
        const int rl = wm * 64 + m * 16 + h * 4 + j;
        const float sq = nrmi[rl] + nj - 2.f * acc[m][n][j];
        const bool same = (labi[rl] == lj);
        if (same) {
          if (row0 + rl != col0 + cl) posr[m][j] = fmaxf(posr[m][j], sq);
        } else {
          negr[m][j] = fminf(negr[m][j], sq);
        }
      }
    }
  }

  // reduce across the 16 col-lanes of each h-group, stash per wave-col
  #pragma unroll
  for (int m = 0; m < 4; ++m) {
    #pragma unroll
    for (int j = 0; j < 4; ++j) {
      float p = posr[m][j], q = negr[m][j];
      #pragma unroll
      for (int mask = 1; mask <= 8; mask <<= 1) {
        p = fmaxf(p, __shfl_xor(p, mask));
        q = fminf(q, __shfl_xor(q, mask));
      }
      if (ccol == 0) {
        const int rl = wm * 64 + m * 16 + h * 4 + j;
        redp[wn][rl] = p; redn[wn][rl] = q;
      }
    }
  }
  __syncthreads();
  if (tid < 128) {
    const float p = fmaxf(redp[0][tid], redp[1][tid]);
    const float q = fminf(redn[0][tid], redn[1][tid]);
    atomicMax(&posk[row0 + tid], enc_f(p));
    atomicMin(&negk[row0 + tid], enc_f(q));
  }
}

__global__ void k_final(const unsigned* __restrict__ posk,
                        const unsigned* __restrict__ negk,
                        float* __restrict__ out) {
  int t = threadIdx.x;  // 1024 threads
  float sum = 0.f;
  int cnt = 0;
  for (int i = t; i < NROWS; i += 1024) {
    float ps = dec_f(posk[i]);
    float ns = dec_f(negk[i]);
    if ((ps > -1e29f) && (ns < 1e29f)) {
      float hp = sqrtf(fmaxf(ps, 1e-12f));
      float hn = sqrtf(fmaxf(ns, 1e-12f));
      sum += fmaxf(hp - hn + MARGINF, 0.f);
      cnt += 1;
    }
  }
  #pragma unroll
  for (int off = 32; off; off >>= 1) {
    sum += __shfl_down(sum, off);
    cnt += __shfl_down(cnt, off);
  }
  __shared__ float wsum[16];
  __shared__ int wcnt[16];
  int w = t >> 6;
  if ((t & 63) == 0) { wsum[w] = sum; wcnt[w] = cnt; }
  __syncthreads();
  if (t == 0) {
    float S = 0.f; int C = 0;
    #pragma unroll
    for (int i = 0; i < 16; ++i) { S += wsum[i]; C += wcnt[i]; }
    out[0] = (C > 0) ? (S / (float)C) : 0.f;
  }
}

extern "C" void kernel_launch(void* const* d_in, const int* in_sizes, int n_in,
                              void* d_out, int out_size, void* d_ws, size_t ws_size,
                              hipStream_t stream) {
  const float* F = (const float*)d_in[0];
  const int* lab = (const int*)d_in[1];
  float* out = (float*)d_out;

  unsigned* posk = (unsigned*)d_ws;                 // [4096]
  unsigned* negk = posk + NROWS;                    // [4096]
  float* nrm = (float*)(negk + NROWS);              // [4096]
  ushort_t* Fb = (ushort_t*)(nrm + NROWS);          // [4096*256] bf16

  k_prep<<<NROWS / 4, 256, 0, stream>>>(F, Fb, nrm, posk, negk);
  k_gram<<<32 * 32, 256, 0, stream>>>(Fb, lab, nrm, posk, negk);
  k_final<<<1, 1024, 0, stream>>>(posk, negk, out);
}